// Round 10
// baseline (429.925 us; speedup 1.0000x reference)
//
#include <hip/hip_runtime.h>
#include <math.h>
#include <stdint.h>

#define NBMAX 1024  // bucket-count bound (NB = ceil(N/128) = 782)
#define BCAP 4864   // per-bucket edge capacity (mean 4096, sigma 64 -> 12 sigma margin)
#define CSTR 16     // cursor stride (ints) -> one counter per 64B L2 line (atomic serialization fix)

typedef __attribute__((ext_vector_type(8))) short short8;
typedef __attribute__((ext_vector_type(4))) float f32x4;

// ---- bf16 helpers (OCP bf16 = upper 16 bits of fp32, RNE) ----
__device__ __forceinline__ unsigned int f2bf(float f) {
    unsigned int u = __float_as_uint(f);
    return (u + 0x7FFFu + ((u >> 16) & 1u)) >> 16;
}
__device__ __forceinline__ float bl(unsigned int u) { return __uint_as_float(u << 16); }
__device__ __forceinline__ float bh(unsigned int u) { return __uint_as_float(u & 0xFFFF0000u); }

// ---------------- init per-bucket cursors (64B-strided) to fixed-capacity bases ----------------
__global__ void k_init(int* __restrict__ cursor) {
    int i = blockIdx.x * 512 + threadIdx.x;
    if (i < NBMAX) cursor[i * CSTR] = i * BCAP;
}

// ---------------- x@W1 via MFMA (split-bf16: hi*hi + lo*hi + hi*lo) ----------------
__global__ __launch_bounds__(256) void k_gemm(
    const float* __restrict__ x, const float* __restrict__ W1,
    float* __restrict__ xw, int n) {
    __shared__ struct { uint4 bhi[1024]; uint4 blo[1024]; } sh;  // [kstep 16][lane 64]
    for (int s = threadIdx.x; s < 1024; s += 256) {
        int ts = s >> 6, l = s & 63;
        int colc = l & 15, kg2 = l >> 4;
        int kbase = ts * 32 + kg2 * 8;
        unsigned int hw[8], lw[8];
#pragma unroll
        for (int j = 0; j < 8; ++j) {
            float wv = W1[(size_t)(kbase + j) * 16 + colc];
            unsigned int u = __float_as_uint(wv);
            unsigned int h = u >> 16;                 // truncated hi
            unsigned int lo = f2bf(wv - bl(h));       // exact residual, RNE to bf16
            hw[j] = h; lw[j] = lo;
        }
        uint4 ph, pl;
        ph.x = hw[0] | (hw[1] << 16); ph.y = hw[2] | (hw[3] << 16);
        ph.z = hw[4] | (hw[5] << 16); ph.w = hw[6] | (hw[7] << 16);
        pl.x = lw[0] | (lw[1] << 16); pl.y = lw[2] | (lw[3] << 16);
        pl.z = lw[4] | (lw[5] << 16); pl.w = lw[6] | (lw[7] << 16);
        sh.bhi[s] = ph; sh.blo[s] = pl;
    }
    __syncthreads();

    int w = threadIdx.x >> 6, lane = threadIdx.x & 63;
    int mtMax = (n + 15) >> 4;
    int mt = blockIdx.x * 4 + w;
    if (mt >= mtMax) return;
    int rowbase = mt * 16;
    int r0 = rowbase + (lane & 15);
    if (r0 >= n) r0 = n - 1;  // clamp
    int kg = lane >> 4;
    const float4* xr = (const float4*)(x + (size_t)r0 * 512);
    f32x4 acc = {0.f, 0.f, 0.f, 0.f};
#pragma unroll 2
    for (int ts = 0; ts < 16; ++ts) {
        float4 u = xr[ts * 8 + kg * 2];
        float4 v = xr[ts * 8 + kg * 2 + 1];
        float e[8] = {u.x, u.y, u.z, u.w, v.x, v.y, v.z, v.w};
        short8 ah, al;
#pragma unroll
        for (int j = 0; j < 8; ++j) {
            unsigned int uu = __float_as_uint(e[j]);
            unsigned int h = uu >> 16;
            unsigned int lo = f2bf(e[j] - bl(h));
            ah[j] = (short)h;
            al[j] = (short)lo;
        }
        uint4 bhw = sh.bhi[ts * 64 + lane];
        uint4 blw = sh.blo[ts * 64 + lane];
        short8 bhv = *reinterpret_cast<const short8*>(&bhw);
        short8 blv = *reinterpret_cast<const short8*>(&blw);
        acc = __builtin_amdgcn_mfma_f32_16x16x32_bf16(ah, bhv, acc, 0, 0, 0);
        acc = __builtin_amdgcn_mfma_f32_16x16x32_bf16(al, bhv, acc, 0, 0, 0);
        acc = __builtin_amdgcn_mfma_f32_16x16x32_bf16(ah, blv, acc, 0, 0, 0);
    }
#pragma unroll
    for (int r = 0; r < 4; ++r) {
        int orow = rowbase + kg * 4 + r;   // D: row=(lane>>4)*4+r, col=lane&15
        if (orow < n) xw[(size_t)orow * 16 + (lane & 15)] = acc[r];
    }
}

// ---------------- bucket-scatter into fixed-capacity regions (LDS staged flush) ----------------
// bucket = col>>7 (128 target nodes); payload w = (row<<7)|(col&127).
// Global space reserved via one atomic per (block,bucket) on 64B-strided cursor.
__global__ __launch_bounds__(512) void k_bucket(
    const int* __restrict__ row, const int* __restrict__ col,
    int* __restrict__ cursor, unsigned int* __restrict__ sortedG, int E) {
    __shared__ int histL[NBMAX];
    __shared__ int offsL[NBMAX];
    __shared__ int gbL[NBMAX];
    __shared__ int sbuf[NBMAX];
    __shared__ unsigned int stageW[4096];
    __shared__ unsigned short stageB[4096];
    int t = threadIdx.x;
    for (int i = t; i < NBMAX; i += 512) histL[i] = 0;
    __syncthreads();
    int off = blockIdx.x * 4096;
    unsigned int w[8]; int bk[8]; int rk[8];
#pragma unroll
    for (int i = 0; i < 8; ++i) {
        int e = off + t + i * 512;
        if (e < E) {
            int c = col[e], r = row[e];
            w[i]  = ((unsigned int)r << 7) | (unsigned int)(c & 127);
            bk[i] = c >> 7;
            rk[i] = atomicAdd(&histL[bk[i]], 1);
        } else bk[i] = -1;
    }
    __syncthreads();
    // 1024-slot Hillis-Steele scan with 512 threads (2 slots each)
    sbuf[t] = histL[t];
    sbuf[t + 512] = histL[t + 512];
    __syncthreads();
    for (int o = 1; o < NBMAX; o <<= 1) {
        int v0 = (t >= o) ? sbuf[t - o] : 0;
        int v1 = (t + 512 >= o) ? sbuf[t + 512 - o] : 0;
        __syncthreads();
        sbuf[t] += v0;
        sbuf[t + 512] += v1;
        __syncthreads();
    }
    for (int s = t; s < NBMAX; s += 512) {
        int cnt = histL[s];
        offsL[s] = sbuf[s] - cnt;
        gbL[s]   = cnt ? atomicAdd(&cursor[s * CSTR], cnt) : 0;
    }
    __syncthreads();
#pragma unroll
    for (int i = 0; i < 8; ++i) {
        if (bk[i] >= 0) {
            int s2 = offsL[bk[i]] + rk[i];
            stageW[s2] = w[i];
            stageB[s2] = (unsigned short)bk[i];
        }
    }
    __syncthreads();
    int total = min(4096, E - off);
    for (int s2 = t; s2 < total; s2 += 512) {
        int b = stageB[s2];
        sortedG[gbL[b] + (s2 - offsL[b])] = stageW[s2];
    }
}

// ---------------- per-bucket (128 nodes): LDS counting sort in place,
//                  per-node offsE/dinv, and scale+bf16 of xw1 ----------------
__global__ __launch_bounds__(512) void k_sortscale(
    unsigned int* __restrict__ sortedG, const int* __restrict__ cursor,
    int2* __restrict__ offsE, float* __restrict__ dinv,
    const float* __restrict__ xw, unsigned int* __restrict__ sxwh, int N) {
    __shared__ unsigned int wv[BCAP];
    __shared__ int hist[128];
    __shared__ int off_[128];
    __shared__ int sc[128];
    __shared__ float ds[128];
    int t = threadIdx.x, b = blockIdx.x;
    if (t < 128) hist[t] = 0;
    __syncthreads();
    int beg = b * BCAP;
    int cnt = cursor[b * CSTR] - beg;
    for (int i = t; i < cnt; i += 512) {
        unsigned int w = sortedG[beg + i];
        wv[i] = w;
        atomicAdd(&hist[w & 127], 1);
    }
    __syncthreads();
    if (t < 128) sc[t] = hist[t];
    __syncthreads();
    for (int o = 1; o < 128; o <<= 1) {
        int v = 0;
        if (t < 128 && t >= o) v = sc[t - o];
        __syncthreads();
        if (t < 128) sc[t] += v;
        __syncthreads();
    }
    if (t < 128) {
        int d = hist[t];
        off_[t] = sc[t] - d;
        int node = b * 128 + t;
        float dv = rsqrtf((float)(d + 1));  // +1 self-loop
        ds[t] = dv;
        if (node < N) {
            int pos = beg + off_[t];
            offsE[node] = make_int2(pos, pos + d);
            dinv[node] = dv;
        }
        hist[t] = 0;  // reuse as pass-2 rank cursor
    }
    __syncthreads();
    // place: node-sorted source rows written back over sortedG (reads via wv)
    for (int i = t; i < cnt; i += 512) {
        unsigned int w = wv[i];
        int c = w & 127;
        int r2 = atomicAdd(&hist[c], 1);
        sortedG[beg + off_[c] + r2] = w >> 7;
    }
    // scale xw1 by dinv and convert to bf16 (bucket's 128-node slab = 512 float4s)
    const float4* xw4 = (const float4*)xw;
    uint2* dsth = (uint2*)sxwh;
    int nl = t >> 2;
    int node = b * 128 + nl;
    if (node < N) {
        float s = ds[nl];
        float4 v = xw4[(size_t)b * 512 + t];
        unsigned int u0 = f2bf(v.x * s), u1 = f2bf(v.y * s);
        unsigned int u2 = f2bf(v.z * s), u3 = f2bf(v.w * s);
        uint2 o; o.x = u0 | (u1 << 16); o.y = u2 | (u3 << 16);
        dsth[(size_t)b * 512 + t] = o;
    }
}

// ---------------- layer-1 pull-gather (bf16 table) + fused fin1 epilogue ----------------
// 4 lanes per node: 2 feature-halves (q) x 2 edge-segments (seg).
__global__ __launch_bounds__(256) void k_gather1f(
    const int2* __restrict__ offsE, const int* __restrict__ srow,
    const uint4* __restrict__ s4, const float* __restrict__ dinv,
    const float* __restrict__ W2, const float* __restrict__ b1,
    float* __restrict__ sxw2p, int N) {
    __shared__ float sW2[112];
    __shared__ float sb1[16];
    if (threadIdx.x < 112) sW2[threadIdx.x] = W2[threadIdx.x];
    if (threadIdx.x < 16) sb1[threadIdx.x] = b1[threadIdx.x];
    __syncthreads();
    int idx = blockIdx.x * 256 + threadIdx.x;
    int node = idx >> 2, sub = idx & 3;
    int q = sub & 1, seg = sub >> 1;
    if (node >= N) return;
    int2 oe = offsE[node];
    int beg0 = oe.x, end0 = oe.y;
    int mid = beg0 + ((end0 - beg0) >> 1);
    int beg = seg ? mid : beg0;
    int end = seg ? end0 : mid;

    float a0 = 0.f, a1 = 0.f, a2 = 0.f, a3 = 0.f;
    float a4 = 0.f, a5 = 0.f, a6 = 0.f, a7 = 0.f;
    if (seg == 0) {  // self-loop once
        uint4 sv = s4[(size_t)node * 2 + q];
        a0 = bl(sv.x); a1 = bh(sv.x); a2 = bl(sv.y); a3 = bh(sv.y);
        a4 = bl(sv.z); a5 = bh(sv.z); a6 = bl(sv.w); a7 = bh(sv.w);
    }
    int j = beg;
    for (; j + 3 < end; j += 4) {
        int r0 = srow[j], r1 = srow[j + 1], r2 = srow[j + 2], r3 = srow[j + 3];
        uint4 v0 = s4[(size_t)r0 * 2 + q];
        uint4 v1 = s4[(size_t)r1 * 2 + q];
        uint4 v2 = s4[(size_t)r2 * 2 + q];
        uint4 v3 = s4[(size_t)r3 * 2 + q];
        a0 += (bl(v0.x) + bl(v1.x)) + (bl(v2.x) + bl(v3.x));
        a1 += (bh(v0.x) + bh(v1.x)) + (bh(v2.x) + bh(v3.x));
        a2 += (bl(v0.y) + bl(v1.y)) + (bl(v2.y) + bl(v3.y));
        a3 += (bh(v0.y) + bh(v1.y)) + (bh(v2.y) + bh(v3.y));
        a4 += (bl(v0.z) + bl(v1.z)) + (bl(v2.z) + bl(v3.z));
        a5 += (bh(v0.z) + bh(v1.z)) + (bh(v2.z) + bh(v3.z));
        a6 += (bl(v0.w) + bl(v1.w)) + (bl(v2.w) + bl(v3.w));
        a7 += (bh(v0.w) + bh(v1.w)) + (bh(v2.w) + bh(v3.w));
    }
    for (; j < end; ++j) {
        int r = srow[j];
        uint4 v = s4[(size_t)r * 2 + q];
        a0 += bl(v.x); a1 += bh(v.x); a2 += bl(v.y); a3 += bh(v.y);
        a4 += bl(v.z); a5 += bh(v.z); a6 += bl(v.w); a7 += bh(v.w);
    }
    // combine edge-segments (lane ^ 2 has same q, other half of edges)
    a0 += __shfl_xor(a0, 2, 64); a1 += __shfl_xor(a1, 2, 64);
    a2 += __shfl_xor(a2, 2, 64); a3 += __shfl_xor(a3, 2, 64);
    a4 += __shfl_xor(a4, 2, 64); a5 += __shfl_xor(a5, 2, 64);
    a6 += __shfl_xor(a6, 2, 64); a7 += __shfl_xor(a7, 2, 64);
    // fin1: h = relu(d*a + b1); o = h @ W2 (pair-split rows, shfl-combine); sxw2p = d*o
    float d = dinv[node];
    float h[8];
    h[0] = fmaxf(fmaf(d, a0, sb1[q * 8 + 0]), 0.f);
    h[1] = fmaxf(fmaf(d, a1, sb1[q * 8 + 1]), 0.f);
    h[2] = fmaxf(fmaf(d, a2, sb1[q * 8 + 2]), 0.f);
    h[3] = fmaxf(fmaf(d, a3, sb1[q * 8 + 3]), 0.f);
    h[4] = fmaxf(fmaf(d, a4, sb1[q * 8 + 4]), 0.f);
    h[5] = fmaxf(fmaf(d, a5, sb1[q * 8 + 5]), 0.f);
    h[6] = fmaxf(fmaf(d, a6, sb1[q * 8 + 6]), 0.f);
    h[7] = fmaxf(fmaf(d, a7, sb1[q * 8 + 7]), 0.f);
    float o[7] = {0.f, 0.f, 0.f, 0.f, 0.f, 0.f, 0.f};
    int rbase = q * 8;
#pragma unroll
    for (int i = 0; i < 8; ++i) {
        float hv = h[i];
#pragma unroll
        for (int jj = 0; jj < 7; ++jj) o[jj] = fmaf(hv, sW2[(rbase + i) * 7 + jj], o[jj]);
    }
#pragma unroll
    for (int jj = 0; jj < 7; ++jj) o[jj] += __shfl_xor(o[jj], 1, 64);
    if (seg == 0) {
        float4 wv4;
        if (q == 0) { wv4.x = o[0] * d; wv4.y = o[1] * d; wv4.z = o[2] * d; wv4.w = o[3] * d; }
        else        { wv4.x = o[4] * d; wv4.y = o[5] * d; wv4.z = o[6] * d; wv4.w = 0.f; }
        ((float4*)sxw2p)[(size_t)node * 2 + q] = wv4;
    }
}

// ---------------- layer-2 pull-gather (fp32 padded table) + fused log_softmax ----------------
// 4 lanes per node: 2 feature-halves (q) x 2 edge-segments (seg).
__global__ __launch_bounds__(256) void k_gather2f(
    const int2* __restrict__ offsE, const int* __restrict__ srow,
    const float* __restrict__ sxw2p, const float* __restrict__ dinv,
    const float* __restrict__ b2, float* __restrict__ out, int N) {
    __shared__ float sb2[8];
    if (threadIdx.x < 7) sb2[threadIdx.x] = b2[threadIdx.x];
    if (threadIdx.x == 7) sb2[7] = 0.f;
    __syncthreads();
    int idx = blockIdx.x * 256 + threadIdx.x;
    int node = idx >> 2, sub = idx & 3;
    int q = sub & 1, seg = sub >> 1;
    if (node >= N) return;
    int2 oe = offsE[node];
    int beg0 = oe.x, end0 = oe.y;
    int mid = beg0 + ((end0 - beg0) >> 1);
    int beg = seg ? mid : beg0;
    int end = seg ? end0 : mid;
    const float4* s4 = (const float4*)sxw2p;
    float4 a = {0.f, 0.f, 0.f, 0.f};
    if (seg == 0) a = s4[(size_t)node * 2 + q];  // self-loop
    int j = beg;
    for (; j + 3 < end; j += 4) {
        int r0 = srow[j], r1 = srow[j + 1], r2 = srow[j + 2], r3 = srow[j + 3];
        float4 v0 = s4[(size_t)r0 * 2 + q];
        float4 v1 = s4[(size_t)r1 * 2 + q];
        float4 v2 = s4[(size_t)r2 * 2 + q];
        float4 v3 = s4[(size_t)r3 * 2 + q];
        a.x += (v0.x + v1.x) + (v2.x + v3.x);
        a.y += (v0.y + v1.y) + (v2.y + v3.y);
        a.z += (v0.z + v1.z) + (v2.z + v3.z);
        a.w += (v0.w + v1.w) + (v2.w + v3.w);
    }
    for (; j < end; ++j) {
        int r = srow[j];
        float4 v = s4[(size_t)r * 2 + q];
        a.x += v.x; a.y += v.y; a.z += v.z; a.w += v.w;
    }
    // combine edge-segments
    a.x += __shfl_xor(a.x, 2, 64); a.y += __shfl_xor(a.y, 2, 64);
    a.z += __shfl_xor(a.z, 2, 64); a.w += __shfl_xor(a.w, 2, 64);
    float d = dinv[node];
    float z0 = fmaf(d, a.x, sb2[q * 4 + 0]);
    float z1 = fmaf(d, a.y, sb2[q * 4 + 1]);
    float z2 = fmaf(d, a.z, sb2[q * 4 + 2]);
    float z3 = (q == 0) ? fmaf(d, a.w, sb2[3]) : -INFINITY;
    float m = fmaxf(fmaxf(z0, z1), fmaxf(z2, z3));
    m = fmaxf(m, __shfl_xor(m, 1, 64));
    float s = expf(z0 - m) + expf(z1 - m) + expf(z2 - m) + ((q == 0) ? expf(z3 - m) : 0.f);
    s += __shfl_xor(s, 1, 64);
    float l = m + logf(s);
    if (seg == 0) {
        float* ob = out + (size_t)node * 7;
        if (q == 0) { ob[0] = z0 - l; ob[1] = z1 - l; ob[2] = z2 - l; ob[3] = z3 - l; }
        else        { ob[4] = z0 - l; ob[5] = z1 - l; ob[6] = z2 - l; }
    }
}

extern "C" void kernel_launch(void* const* d_in, const int* in_sizes, int n_in,
                              void* d_out, int out_size, void* d_ws, size_t ws_size,
                              hipStream_t stream) {
    const float* x  = (const float*)d_in[0];
    const int*   ei = (const int*)d_in[1];
    const float* W1 = (const float*)d_in[2];
    const float* b1 = (const float*)d_in[3];
    const float* W2 = (const float*)d_in[4];
    const float* b2 = (const float*)d_in[5];

    int N = in_sizes[0] / 512;  // 100000
    int E = in_sizes[1] / 2;    // 3200000
    const int* row = ei;        // sources
    const int* col = ei + E;    // targets

    int NB = (N + 127) >> 7;    // 782 buckets of 128 target nodes

    // workspace layout (ints)
    int* cursor = (int*)d_ws;                          // NBMAX*CSTR (64B-strided cursors)
    int2* offsE = (int2*)(cursor + NBMAX * CSTR);      // N int2 (beg,end)
    float* dinv = (float*)(offsE + N);                 // N
    unsigned int* sortedG = (unsigned int*)(dinv + N); // NB*BCAP packed edges -> rows
    float* xw1  = (float*)(sortedG + (size_t)NBMAX * BCAP);  // 16N fp32
    unsigned int* sxwh = (unsigned int*)(xw1 + (size_t)16 * N);  // 8N = [N,16] bf16
    float* sxw2p = xw1;                                // 8N, aliases dead xw1
    float* out   = (float*)d_out;

    int mtMax = (N + 15) / 16;           // 6250 M-tiles
    int gM = (mtMax + 3) / 4;            // 1563 MFMA gemm blocks
    int bB = (E + 4095) / 4096;          // 782 bucket blocks
    int gP = (4 * N + 255) / 256;        // 1563 gather blocks (4 lanes/node)

    k_init     <<<2, 512, 0, stream>>>(cursor);
    k_gemm     <<<gM, 256, 0, stream>>>(x, W1, xw1, N);
    k_bucket   <<<bB, 512, 0, stream>>>(row, col, cursor, sortedG, E);
    k_sortscale<<<NB, 512, 0, stream>>>(sortedG, cursor, offsE, dinv, xw1, sxwh, N);
    k_gather1f <<<gP, 256, 0, stream>>>(offsE, (const int*)sortedG, (const uint4*)sxwh,
                                        dinv, W2, b1, sxw2p, N);
    k_gather2f <<<gP, 256, 0, stream>>>(offsE, (const int*)sortedG, sxw2p, dinv, b2, out, N);
}

// Round 11
// 395.869 us; speedup vs baseline: 1.0860x; 1.0860x over previous
//
#include <hip/hip_runtime.h>
#include <math.h>
#include <stdint.h>

#define NBMAX 1024  // bucket-count bound (NB = ceil(N/128) = 782)
#define BCAP 4864   // per-bucket edge capacity (mean 4096, sigma 64 -> 12 sigma margin)

typedef __attribute__((ext_vector_type(8))) short short8;
typedef __attribute__((ext_vector_type(4))) float f32x4;

// ---- bf16 helpers (OCP bf16 = upper 16 bits of fp32, RNE) ----
__device__ __forceinline__ unsigned int f2bf(float f) {
    unsigned int u = __float_as_uint(f);
    return (u + 0x7FFFu + ((u >> 16) & 1u)) >> 16;
}
__device__ __forceinline__ float bl(unsigned int u) { return __uint_as_float(u << 16); }
__device__ __forceinline__ float bh(unsigned int u) { return __uint_as_float(u & 0xFFFF0000u); }

// ---------------- init per-bucket cursors to fixed-capacity bases ----------------
__global__ void k_init(int* __restrict__ cursor) {
    int i = blockIdx.x * 512 + threadIdx.x;
    if (i < NBMAX) cursor[i] = i * BCAP;
}

// ---------------- fused bucket-scatter + x@W1 MFMA gemm (interleaved block roles) ----------------
// Even blocks: bucket-scatter 4096 edges into fixed-capacity regions (LDS staged flush).
// Odd blocks: 8 waves x 16-row M-tiles of split-bf16 MFMA gemm.
// The two roles are independent (bucket: row/col->sortedG; gemm: x->xw) and
// pipe-complementary (LDS-atomic/barrier vs memory/MFMA) -> co-residency overlap.
__global__ __launch_bounds__(512) void k_bg(
    const int* __restrict__ row, const int* __restrict__ col,
    int* __restrict__ cursor, unsigned int* __restrict__ sortedG, int E, int bB,
    const float* __restrict__ x, const float* __restrict__ W1,
    float* __restrict__ xw, int n) {
    __shared__ union {
        struct {
            int histL[NBMAX]; int offsL[NBMAX]; int gbL[NBMAX]; int sbuf[NBMAX];
            unsigned int stageW[4096]; unsigned short stageB[4096];
        } b;                                           // 40 KB
        struct { uint4 bhi[1024]; uint4 blo[1024]; } g;  // 32 KB
    } sh;
    int t = threadIdx.x;
    int pair = blockIdx.x >> 1;

    if ((blockIdx.x & 1) == 0) {
        // ================= bucket role =================
        if (pair >= bB) return;
        for (int i = t; i < NBMAX; i += 512) sh.b.histL[i] = 0;
        __syncthreads();
        int off = pair * 4096;
        unsigned int w[8]; int bk[8]; int rk[8];
#pragma unroll
        for (int i = 0; i < 8; ++i) {
            int e = off + t + i * 512;
            if (e < E) {
                int c = col[e], r = row[e];
                w[i]  = ((unsigned int)r << 7) | (unsigned int)(c & 127);
                bk[i] = c >> 7;
                rk[i] = atomicAdd(&sh.b.histL[bk[i]], 1);
            } else bk[i] = -1;
        }
        __syncthreads();
        // 1024-slot Hillis-Steele scan with 512 threads (2 slots each)
        sh.b.sbuf[t] = sh.b.histL[t];
        sh.b.sbuf[t + 512] = sh.b.histL[t + 512];
        __syncthreads();
        for (int o = 1; o < NBMAX; o <<= 1) {
            int v0 = (t >= o) ? sh.b.sbuf[t - o] : 0;
            int v1 = (t + 512 >= o) ? sh.b.sbuf[t + 512 - o] : 0;
            __syncthreads();
            sh.b.sbuf[t] += v0;
            sh.b.sbuf[t + 512] += v1;
            __syncthreads();
        }
        for (int s = t; s < NBMAX; s += 512) {
            int cnt = sh.b.histL[s];
            sh.b.offsL[s] = sh.b.sbuf[s] - cnt;
            sh.b.gbL[s]   = cnt ? atomicAdd(&cursor[s], cnt) : 0;
        }
        __syncthreads();
#pragma unroll
        for (int i = 0; i < 8; ++i) {
            if (bk[i] >= 0) {
                int s2 = sh.b.offsL[bk[i]] + rk[i];
                sh.b.stageW[s2] = w[i];
                sh.b.stageB[s2] = (unsigned short)bk[i];
            }
        }
        __syncthreads();
        int total = min(4096, E - off);
        for (int s2 = t; s2 < total; s2 += 512) {
            int b = sh.b.stageB[s2];
            sortedG[sh.b.gbL[b] + (s2 - sh.b.offsL[b])] = sh.b.stageW[s2];
        }
        return;
    }

    // ================= gemm role =================
    for (int s = t; s < 1024; s += 512) {
        int ts = s >> 6, l = s & 63;
        int colc = l & 15, kg2 = l >> 4;
        int kbase = ts * 32 + kg2 * 8;
        unsigned int hw[8], lw[8];
#pragma unroll
        for (int j = 0; j < 8; ++j) {
            float wv = W1[(size_t)(kbase + j) * 16 + colc];
            unsigned int u = __float_as_uint(wv);
            unsigned int h = u >> 16;                 // truncated hi
            unsigned int lo = f2bf(wv - bl(h));       // exact residual, RNE to bf16
            hw[j] = h; lw[j] = lo;
        }
        uint4 ph, pl;
        ph.x = hw[0] | (hw[1] << 16); ph.y = hw[2] | (hw[3] << 16);
        ph.z = hw[4] | (hw[5] << 16); ph.w = hw[6] | (hw[7] << 16);
        pl.x = lw[0] | (lw[1] << 16); pl.y = lw[2] | (lw[3] << 16);
        pl.z = lw[4] | (lw[5] << 16); pl.w = lw[6] | (lw[7] << 16);
        sh.g.bhi[s] = ph; sh.g.blo[s] = pl;
    }
    __syncthreads();

    int w = t >> 6, lane = t & 63;
    int mtMax = (n + 15) >> 4;
    int mt = pair * 8 + w;
    if (mt >= mtMax) return;
    int rowbase = mt * 16;
    int r0 = rowbase + (lane & 15);
    if (r0 >= n) r0 = n - 1;  // clamp
    int kg = lane >> 4;
    const float4* xr = (const float4*)(x + (size_t)r0 * 512);
    f32x4 acc = {0.f, 0.f, 0.f, 0.f};
#pragma unroll 2
    for (int ts = 0; ts < 16; ++ts) {
        float4 u = xr[ts * 8 + kg * 2];
        float4 v = xr[ts * 8 + kg * 2 + 1];
        float e[8] = {u.x, u.y, u.z, u.w, v.x, v.y, v.z, v.w};
        short8 ah, al;
#pragma unroll
        for (int j = 0; j < 8; ++j) {
            unsigned int uu = __float_as_uint(e[j]);
            unsigned int h = uu >> 16;
            unsigned int lo = f2bf(e[j] - bl(h));
            ah[j] = (short)h;
            al[j] = (short)lo;
        }
        uint4 bhw = sh.g.bhi[ts * 64 + lane];
        uint4 blw = sh.g.blo[ts * 64 + lane];
        short8 bhv = *reinterpret_cast<const short8*>(&bhw);
        short8 blv = *reinterpret_cast<const short8*>(&blw);
        acc = __builtin_amdgcn_mfma_f32_16x16x32_bf16(ah, bhv, acc, 0, 0, 0);
        acc = __builtin_amdgcn_mfma_f32_16x16x32_bf16(al, bhv, acc, 0, 0, 0);
        acc = __builtin_amdgcn_mfma_f32_16x16x32_bf16(ah, blv, acc, 0, 0, 0);
    }
#pragma unroll
    for (int r = 0; r < 4; ++r) {
        int orow = rowbase + kg * 4 + r;   // D: row=(lane>>4)*4+r, col=lane&15
        if (orow < n) xw[(size_t)orow * 16 + (lane & 15)] = acc[r];
    }
}

// ---------------- per-bucket (128 nodes): LDS counting sort in place,
//                  per-node offsE/dinv, and scale+bf16 of xw1 ----------------
__global__ __launch_bounds__(512) void k_sortscale(
    unsigned int* __restrict__ sortedG, const int* __restrict__ cursor,
    int2* __restrict__ offsE, float* __restrict__ dinv,
    const float* __restrict__ xw, unsigned int* __restrict__ sxwh, int N) {
    __shared__ unsigned int wv[BCAP];
    __shared__ int hist[128];
    __shared__ int off_[128];
    __shared__ int sc[128];
    __shared__ float ds[128];
    int t = threadIdx.x, b = blockIdx.x;
    if (t < 128) hist[t] = 0;
    __syncthreads();
    int beg = b * BCAP;
    int cnt = cursor[b] - beg;
    for (int i = t; i < cnt; i += 512) {
        unsigned int w = sortedG[beg + i];
        wv[i] = w;
        atomicAdd(&hist[w & 127], 1);
    }
    __syncthreads();
    if (t < 128) sc[t] = hist[t];
    __syncthreads();
    for (int o = 1; o < 128; o <<= 1) {
        int v = 0;
        if (t < 128 && t >= o) v = sc[t - o];
        __syncthreads();
        if (t < 128) sc[t] += v;
        __syncthreads();
    }
    if (t < 128) {
        int d = hist[t];
        off_[t] = sc[t] - d;
        int node = b * 128 + t;
        float dv = rsqrtf((float)(d + 1));  // +1 self-loop
        ds[t] = dv;
        if (node < N) {
            int pos = beg + off_[t];
            offsE[node] = make_int2(pos, pos + d);
            dinv[node] = dv;
        }
        hist[t] = 0;  // reuse as pass-2 rank cursor
    }
    __syncthreads();
    // place: node-sorted source rows written back over sortedG (reads via wv)
    for (int i = t; i < cnt; i += 512) {
        unsigned int w = wv[i];
        int c = w & 127;
        int r2 = atomicAdd(&hist[c], 1);
        sortedG[beg + off_[c] + r2] = w >> 7;
    }
    // scale xw1 by dinv and convert to bf16 (bucket's 128-node slab = 512 float4s)
    const float4* xw4 = (const float4*)xw;
    uint2* dsth = (uint2*)sxwh;
    int nl = t >> 2;
    int node = b * 128 + nl;
    if (node < N) {
        float s = ds[nl];
        float4 v = xw4[(size_t)b * 512 + t];
        unsigned int u0 = f2bf(v.x * s), u1 = f2bf(v.y * s);
        unsigned int u2 = f2bf(v.z * s), u3 = f2bf(v.w * s);
        uint2 o; o.x = u0 | (u1 << 16); o.y = u2 | (u3 << 16);
        dsth[(size_t)b * 512 + t] = o;
    }
}

// ---------------- layer-1 pull-gather (bf16 table) + fused fin1 epilogue ----------------
// 4 lanes per node: 2 feature-halves (q) x 2 edge-segments (seg).
__global__ __launch_bounds__(256) void k_gather1f(
    const int2* __restrict__ offsE, const int* __restrict__ srow,
    const uint4* __restrict__ s4, const float* __restrict__ dinv,
    const float* __restrict__ W2, const float* __restrict__ b1,
    float* __restrict__ sxw2p, int N) {
    __shared__ float sW2[112];
    __shared__ float sb1[16];
    if (threadIdx.x < 112) sW2[threadIdx.x] = W2[threadIdx.x];
    if (threadIdx.x < 16) sb1[threadIdx.x] = b1[threadIdx.x];
    __syncthreads();
    int idx = blockIdx.x * 256 + threadIdx.x;
    int node = idx >> 2, sub = idx & 3;
    int q = sub & 1, seg = sub >> 1;
    if (node >= N) return;
    int2 oe = offsE[node];
    int beg0 = oe.x, end0 = oe.y;
    int mid = beg0 + ((end0 - beg0) >> 1);
    int beg = seg ? mid : beg0;
    int end = seg ? end0 : mid;

    float a0 = 0.f, a1 = 0.f, a2 = 0.f, a3 = 0.f;
    float a4 = 0.f, a5 = 0.f, a6 = 0.f, a7 = 0.f;
    if (seg == 0) {  // self-loop once
        uint4 sv = s4[(size_t)node * 2 + q];
        a0 = bl(sv.x); a1 = bh(sv.x); a2 = bl(sv.y); a3 = bh(sv.y);
        a4 = bl(sv.z); a5 = bh(sv.z); a6 = bl(sv.w); a7 = bh(sv.w);
    }
    int j = beg;
    for (; j + 3 < end; j += 4) {
        int r0 = srow[j], r1 = srow[j + 1], r2 = srow[j + 2], r3 = srow[j + 3];
        uint4 v0 = s4[(size_t)r0 * 2 + q];
        uint4 v1 = s4[(size_t)r1 * 2 + q];
        uint4 v2 = s4[(size_t)r2 * 2 + q];
        uint4 v3 = s4[(size_t)r3 * 2 + q];
        a0 += (bl(v0.x) + bl(v1.x)) + (bl(v2.x) + bl(v3.x));
        a1 += (bh(v0.x) + bh(v1.x)) + (bh(v2.x) + bh(v3.x));
        a2 += (bl(v0.y) + bl(v1.y)) + (bl(v2.y) + bl(v3.y));
        a3 += (bh(v0.y) + bh(v1.y)) + (bh(v2.y) + bh(v3.y));
        a4 += (bl(v0.z) + bl(v1.z)) + (bl(v2.z) + bl(v3.z));
        a5 += (bh(v0.z) + bh(v1.z)) + (bh(v2.z) + bh(v3.z));
        a6 += (bl(v0.w) + bl(v1.w)) + (bl(v2.w) + bl(v3.w));
        a7 += (bh(v0.w) + bh(v1.w)) + (bh(v2.w) + bh(v3.w));
    }
    for (; j < end; ++j) {
        int r = srow[j];
        uint4 v = s4[(size_t)r * 2 + q];
        a0 += bl(v.x); a1 += bh(v.x); a2 += bl(v.y); a3 += bh(v.y);
        a4 += bl(v.z); a5 += bh(v.z); a6 += bl(v.w); a7 += bh(v.w);
    }
    // combine edge-segments (lane ^ 2 has same q, other half of edges)
    a0 += __shfl_xor(a0, 2, 64); a1 += __shfl_xor(a1, 2, 64);
    a2 += __shfl_xor(a2, 2, 64); a3 += __shfl_xor(a3, 2, 64);
    a4 += __shfl_xor(a4, 2, 64); a5 += __shfl_xor(a5, 2, 64);
    a6 += __shfl_xor(a6, 2, 64); a7 += __shfl_xor(a7, 2, 64);
    // fin1: h = relu(d*a + b1); o = h @ W2 (pair-split rows, shfl-combine); sxw2p = d*o
    float d = dinv[node];
    float h[8];
    h[0] = fmaxf(fmaf(d, a0, sb1[q * 8 + 0]), 0.f);
    h[1] = fmaxf(fmaf(d, a1, sb1[q * 8 + 1]), 0.f);
    h[2] = fmaxf(fmaf(d, a2, sb1[q * 8 + 2]), 0.f);
    h[3] = fmaxf(fmaf(d, a3, sb1[q * 8 + 3]), 0.f);
    h[4] = fmaxf(fmaf(d, a4, sb1[q * 8 + 4]), 0.f);
    h[5] = fmaxf(fmaf(d, a5, sb1[q * 8 + 5]), 0.f);
    h[6] = fmaxf(fmaf(d, a6, sb1[q * 8 + 6]), 0.f);
    h[7] = fmaxf(fmaf(d, a7, sb1[q * 8 + 7]), 0.f);
    float o[7] = {0.f, 0.f, 0.f, 0.f, 0.f, 0.f, 0.f};
    int rbase = q * 8;
#pragma unroll
    for (int i = 0; i < 8; ++i) {
        float hv = h[i];
#pragma unroll
        for (int jj = 0; jj < 7; ++jj) o[jj] = fmaf(hv, sW2[(rbase + i) * 7 + jj], o[jj]);
    }
#pragma unroll
    for (int jj = 0; jj < 7; ++jj) o[jj] += __shfl_xor(o[jj], 1, 64);
    if (seg == 0) {
        float4 wv4;
        if (q == 0) { wv4.x = o[0] * d; wv4.y = o[1] * d; wv4.z = o[2] * d; wv4.w = o[3] * d; }
        else        { wv4.x = o[4] * d; wv4.y = o[5] * d; wv4.z = o[6] * d; wv4.w = 0.f; }
        ((float4*)sxw2p)[(size_t)node * 2 + q] = wv4;
    }
}

// ---------------- layer-2 pull-gather (fp32 padded table) + fused log_softmax ----------------
// 4 lanes per node: 2 feature-halves (q) x 2 edge-segments (seg).
__global__ __launch_bounds__(256) void k_gather2f(
    const int2* __restrict__ offsE, const int* __restrict__ srow,
    const float* __restrict__ sxw2p, const float* __restrict__ dinv,
    const float* __restrict__ b2, float* __restrict__ out, int N) {
    __shared__ float sb2[8];
    if (threadIdx.x < 7) sb2[threadIdx.x] = b2[threadIdx.x];
    if (threadIdx.x == 7) sb2[7] = 0.f;
    __syncthreads();
    int idx = blockIdx.x * 256 + threadIdx.x;
    int node = idx >> 2, sub = idx & 3;
    int q = sub & 1, seg = sub >> 1;
    if (node >= N) return;
    int2 oe = offsE[node];
    int beg0 = oe.x, end0 = oe.y;
    int mid = beg0 + ((end0 - beg0) >> 1);
    int beg = seg ? mid : beg0;
    int end = seg ? end0 : mid;
    const float4* s4 = (const float4*)sxw2p;
    float4 a = {0.f, 0.f, 0.f, 0.f};
    if (seg == 0) a = s4[(size_t)node * 2 + q];  // self-loop
    int j = beg;
    for (; j + 3 < end; j += 4) {
        int r0 = srow[j], r1 = srow[j + 1], r2 = srow[j + 2], r3 = srow[j + 3];
        float4 v0 = s4[(size_t)r0 * 2 + q];
        float4 v1 = s4[(size_t)r1 * 2 + q];
        float4 v2 = s4[(size_t)r2 * 2 + q];
        float4 v3 = s4[(size_t)r3 * 2 + q];
        a.x += (v0.x + v1.x) + (v2.x + v3.x);
        a.y += (v0.y + v1.y) + (v2.y + v3.y);
        a.z += (v0.z + v1.z) + (v2.z + v3.z);
        a.w += (v0.w + v1.w) + (v2.w + v3.w);
    }
    for (; j < end; ++j) {
        int r = srow[j];
        float4 v = s4[(size_t)r * 2 + q];
        a.x += v.x; a.y += v.y; a.z += v.z; a.w += v.w;
    }
    // combine edge-segments
    a.x += __shfl_xor(a.x, 2, 64); a.y += __shfl_xor(a.y, 2, 64);
    a.z += __shfl_xor(a.z, 2, 64); a.w += __shfl_xor(a.w, 2, 64);
    float d = dinv[node];
    float z0 = fmaf(d, a.x, sb2[q * 4 + 0]);
    float z1 = fmaf(d, a.y, sb2[q * 4 + 1]);
    float z2 = fmaf(d, a.z, sb2[q * 4 + 2]);
    float z3 = (q == 0) ? fmaf(d, a.w, sb2[3]) : -INFINITY;
    float m = fmaxf(fmaxf(z0, z1), fmaxf(z2, z3));
    m = fmaxf(m, __shfl_xor(m, 1, 64));
    float s = expf(z0 - m) + expf(z1 - m) + expf(z2 - m) + ((q == 0) ? expf(z3 - m) : 0.f);
    s += __shfl_xor(s, 1, 64);
    float l = m + logf(s);
    if (seg == 0) {
        float* ob = out + (size_t)node * 7;
        if (q == 0) { ob[0] = z0 - l; ob[1] = z1 - l; ob[2] = z2 - l; ob[3] = z3 - l; }
        else        { ob[4] = z0 - l; ob[5] = z1 - l; ob[6] = z2 - l; }
    }
}

extern "C" void kernel_launch(void* const* d_in, const int* in_sizes, int n_in,
                              void* d_out, int out_size, void* d_ws, size_t ws_size,
                              hipStream_t stream) {
    const float* x  = (const float*)d_in[0];
    const int*   ei = (const int*)d_in[1];
    const float* W1 = (const float*)d_in[2];
    const float* b1 = (const float*)d_in[3];
    const float* W2 = (const float*)d_in[4];
    const float* b2 = (const float*)d_in[5];

    int N = in_sizes[0] / 512;  // 100000
    int E = in_sizes[1] / 2;    // 3200000
    const int* row = ei;        // sources
    const int* col = ei + E;    // targets

    int NB = (N + 127) >> 7;    // 782 buckets of 128 target nodes

    // workspace layout (ints)
    int* cursor = (int*)d_ws;                          // NBMAX
    int2* offsE = (int2*)(cursor + NBMAX);             // N int2 (beg,end)
    float* dinv = (float*)(offsE + N);                 // N
    unsigned int* sortedG = (unsigned int*)(dinv + N); // NB*BCAP packed edges -> rows
    float* xw1  = (float*)(sortedG + (size_t)NBMAX * BCAP);  // 16N fp32
    unsigned int* sxwh = (unsigned int*)(xw1 + (size_t)16 * N);  // 8N = [N,16] bf16
    float* sxw2p = xw1;                                // 8N, aliases dead xw1
    float* out   = (float*)d_out;

    int mtMax = (N + 15) / 16;           // 6250 M-tiles
    int gM8 = (mtMax + 7) / 8;           // 782 gemm pairs (8 waves x 16-row tiles)
    int bB  = (E + 4095) / 4096;         // 782 bucket pairs
    int nPair = (bB > gM8) ? bB : gM8;   // 782
    int gP = (4 * N + 255) / 256;        // 1563 gather blocks (4 lanes/node)

    k_init     <<<2, 512, 0, stream>>>(cursor);
    k_bg       <<<2 * nPair, 512, 0, stream>>>(row, col, cursor, sortedG, E, bB,
                                               x, W1, xw1, N);
    k_sortscale<<<NB, 512, 0, stream>>>(sortedG, cursor, offsE, dinv, xw1, sxwh, N);
    k_gather1f <<<gP, 256, 0, stream>>>(offsE, (const int*)sortedG, (const uint4*)sxwh,
                                        dinv, W2, b1, sxw2p, N);
    k_gather2f <<<gP, 256, 0, stream>>>(offsE, (const int*)sortedG, sxw2p, dinv, b2, out, N);
}